// Round 4
// baseline (120.988 us; speedup 1.0000x reference)
//
#include <hip/hip_runtime.h>

// Problem constants
#define D_B 8
#define N_T 2048
#define NN  64
#define N_H 8
#define N_C 32   // u-chunks of 64
#define NP  72   // padded LDS row stride (bf16): 144 B rows, 16B-aligned, 2-way alias (free)

typedef __bf16 bf16;
typedef bf16 bf16x8 __attribute__((ext_vector_type(8)));
typedef bf16 bf16x4 __attribute__((ext_vector_type(4)));
typedef float f32x4 __attribute__((ext_vector_type(4)));

static __device__ __forceinline__ f32x4 mfma16(bf16x8 a, bf16x8 b, f32x4 c) {
    // a_frag[j] = A[lane&15][(lane>>4)*8+j]; b_frag[j] = B[(lane>>4)*8+j][lane&15]
    // d[r] = D[(lane>>4)*4+r][lane&15]
    return __builtin_amdgcn_mfma_f32_16x16x32_bf16(a, b, c, 0, 0, 0);
}

static __device__ __forceinline__ bf16x8 ldcvt8(const float* p) {
    const f32x4 v0 = *(const f32x4*)p;
    const f32x4 v1 = *(const f32x4*)(p + 4);
    bf16x8 r;
#pragma unroll
    for (int k = 0; k < 4; k++) { r[k] = (bf16)v0[k]; r[4 + k] = (bf16)v1[k]; }
    return r;
}

// ---------------------------------------------------------------------------
// K1'' (R4): block (b, c, zz) handles heads {2zz, 2zz+1}. Same math as the
// R3-proven K1', restructured for critical path:
//   - Q/E B-frags loaded DIRECTLY from global fp32 (L2/L3-hot, 128 KB total)
//     -> no Ql/El staging, no stage barrier. Address pattern identical to the
//     proven Ql/El reads with row stride 64 instead of NP.
//   - 2 barriers/head (was 4): seg1 {Qr/Er MFMA -> QT/ET/QT2}, barrier,
//     seg2 {dG MFMA + diag-S MFMA -> S (aliases wave-own QT rows, same-wave
//     in-order DS) -> PV MFMA}, barrier.
//   - LDS 27 KB (QT + QT2 + ET); 5 barriers/block total (was 9).
// Outputs unchanged: dGq (bf16 [i][i']), diagq (fp32 diag partials).
// Grid (D_B, N_C, 4): linear%8 = b (XCD-local).
// ---------------------------------------------------------------------------
__global__ __launch_bounds__(256, 4) void k_dg(
    const float* __restrict__ rp, const float* __restrict__ Qm,
    const float* __restrict__ Em,
    bf16* __restrict__ dGq, float* __restrict__ diagq)
{
    __shared__ __align__(16) char smem[3 * 64 * NP * 2];  // 27648 B
    bf16* QT  = (bf16*)smem;       // Qr [i][u]; per-wave S slabs alias own rows
    bf16* QT2 = QT + 64 * NP;      // Qr [u][i]
    bf16* ET  = QT2 + 64 * NP;     // Er [i][u]; tail: dG staging [i][i']
    float* fst = (float*)smem;     // tail: fp32 diag staging 64x66 (QT+QT2 region)

    const int b = blockIdx.x, c = blockIdx.y, zz = blockIdx.z;
    const int tid = threadIdx.x;
    const int w = tid >> 6, l = tid & 63, q = l >> 4, l16 = l & 15;
    const int row = tid >> 2, col = (tid & 3) * 16;

    // A-frags: r' rows u = t = c*64 + w*16 + l16 (shared by Qr/Er/S paths)
    const float* rrow = rp + ((size_t)b * N_T + c * 64 + w * 16 + l16) * NN;
    const bf16x8 a0 = ldcvt8(rrow + q * 8);
    const bf16x8 a1 = ldcvt8(rrow + 32 + q * 8);

    f32x4 dacc[4], acc[4];
#pragma unroll
    for (int ns = 0; ns < 4; ns++) {
        f32x4 z = {0.f, 0.f, 0.f, 0.f};
        dacc[ns] = z; acc[ns] = z;
    }

    for (int hh = 0; hh < 2; hh++) {
        const int h = zz * 2 + hh;
        const float* Qh = Qm + (size_t)h * 4096;
        const float* Eh = Em + (size_t)h * 4096;
        bf16x4 pq[4];
        // ---- segment 1: Qr/Er for this wave's 16 u-rows; B-frags from global
#pragma unroll
        for (int ns = 0; ns < 4; ns++) {
            const float* qp = Qh + (ns * 16 + l16) * 64 + q * 8;
            const bf16x8 qb0 = ldcvt8(qp);
            const bf16x8 qb1 = ldcvt8(qp + 32);
            f32x4 z = {0.f, 0.f, 0.f, 0.f};
            f32x4 s = mfma16(a0, qb0, z);
            s = mfma16(a1, qb1, s);
            bf16x4 p;
#pragma unroll
            for (int r = 0; r < 4; r++) p[r] = (bf16)s[r];
            pq[ns] = p;
            *(bf16x4*)&QT[(ns * 16 + l16) * NP + w * 16 + q * 4] = p;  // [i][u]
            const float* ep = Eh + (ns * 16 + l16) * 64 + q * 8;
            const bf16x8 eb0 = ldcvt8(ep);
            const bf16x8 eb1 = ldcvt8(ep + 32);
            f32x4 s2 = mfma16(a0, eb0, z);
            s2 = mfma16(a1, eb1, s2);
#pragma unroll
            for (int r = 0; r < 4; r++) p[r] = (bf16)s2[r];
            *(bf16x4*)&ET[(ns * 16 + l16) * NP + w * 16 + q * 4] = p;  // [i][u]
        }
        // QT2 [u][i] from pq (wave-own rows, no cross-wave conflict)
#pragma unroll
        for (int ns = 0; ns < 4; ns++)
#pragma unroll
            for (int r = 0; r < 4; r++)
                QT2[(w * 16 + q * 4 + r) * NP + ns * 16 + l16] = pq[ns][r];
        __syncthreads();  // barrier 1: QT/ET/QT2 ready
        // ---- segment 2: dG + diag, then PV
        {
            // dG += Qr^T.Er (A from wave-own QT rows — read BEFORE S overwrites)
            const bf16x8 qa0 = *(const bf16x8*)&QT[(w * 16 + l16) * NP + q * 8];
            const bf16x8 qa1 = *(const bf16x8*)&QT[(w * 16 + l16) * NP + 32 + q * 8];
#pragma unroll
            for (int ns = 0; ns < 4; ns++) {
                const bf16x8 e0 = *(const bf16x8*)&ET[(ns * 16 + l16) * NP + q * 8];
                const bf16x8 e1 = *(const bf16x8*)&ET[(ns * 16 + l16) * NP + 32 + q * 8];
                dacc[ns] = mfma16(qa0, e0, dacc[ns]);
                dacc[ns] = mfma16(qa1, e1, dacc[ns]);
            }
            // diag-S: S[t][u] = mask(r_t . Qr_u^T); S slab = wave-own QT rows
            bf16* Sw = QT + (w * 16) * NP;
#pragma unroll
            for (int nu = 0; nu < 4; nu++) {
                if (nu <= w) {
                    const bf16x8 sb0 = *(const bf16x8*)&QT2[(nu * 16 + l16) * NP + q * 8];
                    const bf16x8 sb1 = *(const bf16x8*)&QT2[(nu * 16 + l16) * NP + 32 + q * 8];
                    f32x4 z = {0.f, 0.f, 0.f, 0.f};
                    f32x4 sv = mfma16(a0, sb0, z);
                    sv = mfma16(a1, sb1, sv);
                    const int u_loc = nu * 16 + l16;
#pragma unroll
                    for (int r = 0; r < 4; r++) {
                        const int t_loc = w * 16 + q * 4 + r;
                        Sw[(q * 4 + r) * NP + u_loc] = (u_loc <= t_loc) ? (bf16)sv[r] : (bf16)0.f;
                    }
                } else {
#pragma unroll
                    for (int r = 0; r < 4; r++)
                        Sw[(q * 4 + r) * NP + nu * 16 + l16] = (bf16)0.f;
                }
            }
            // same-wave in-order DS read-back; PV: acc += S.Er
            const bf16x8 sa0 = *(const bf16x8*)&Sw[l16 * NP + q * 8];
#pragma unroll
            for (int ns = 0; ns < 4; ns++) {
                const bf16x8 e0 = *(const bf16x8*)&ET[(ns * 16 + l16) * NP + q * 8];
                acc[ns] = mfma16(sa0, e0, acc[ns]);
            }
            if (w >= 2) {
                const bf16x8 sa1 = *(const bf16x8*)&Sw[l16 * NP + 32 + q * 8];
#pragma unroll
                for (int ns = 0; ns < 4; ns++) {
                    const bf16x8 e1 = *(const bf16x8*)&ET[(ns * 16 + l16) * NP + 32 + q * 8];
                    acc[ns] = mfma16(sa1, e1, acc[ns]);
                }
            }
        }
        __syncthreads();  // barrier 2: end of head (all LDS consumed)
    }
    // ---- tail: stage dG (bf16 [i][i'] -> ET) and diag (fp32 -> fst)
#pragma unroll
    for (int ns = 0; ns < 4; ns++) {
        bf16x4 p;
#pragma unroll
        for (int r = 0; r < 4; r++) p[r] = (bf16)dacc[ns][r];
        *(bf16x4*)&ET[(ns * 16 + l16) * NP + w * 16 + q * 4] = p;
    }
#pragma unroll
    for (int ns = 0; ns < 4; ns++)
#pragma unroll
        for (int r = 0; r < 4; r++)
            fst[(w * 16 + q * 4 + r) * 66 + ns * 16 + l16] = acc[ns][r];
    __syncthreads();  // barrier 3 (tail)
    {
        bf16* dst = dGq + (((size_t)(b * N_C + c)) * 4 + zz) * 4096 + row * 64 + col;
        *(bf16x8*)dst       = *(const bf16x8*)&ET[row * NP + col];
        *(bf16x8*)(dst + 8) = *(const bf16x8*)&ET[row * NP + col + 8];
        float* dd = diagq + (((size_t)(b * N_C + c)) * 4 + zz) * 4096 + row * 64 + col;
#pragma unroll
        for (int k = 0; k < 4; k++)
            *(f32x4*)(dd + k * 4) = *(const f32x4*)&fst[row * 66 + col + k * 4];
    }
}

// ---------------------------------------------------------------------------
// K2: fold the 4 head-quarters: dG8[b,c] = sum_qt dGq[b,c,qt]. (proven)
// ---------------------------------------------------------------------------
__global__ __launch_bounds__(256, 4) void k_fold(const bf16* __restrict__ dGq,
                                                 bf16* __restrict__ dG8)
{
    const int b = blockIdx.x, c = blockIdx.y;
    const size_t base = ((size_t)(b * N_C + c)) * 4 * 4096 + threadIdx.x * 16;
    float s[16];
#pragma unroll
    for (int k = 0; k < 16; k++) s[k] = 0.f;
#pragma unroll
    for (int qt = 0; qt < 4; qt++) {
        const bf16x8 v0 = *(const bf16x8*)(dGq + base + (size_t)qt * 4096);
        const bf16x8 v1 = *(const bf16x8*)(dGq + base + (size_t)qt * 4096 + 8);
#pragma unroll
        for (int k = 0; k < 8; k++) { s[k] += (float)v0[k]; s[8 + k] += (float)v1[k]; }
    }
    bf16x8 o0, o1;
#pragma unroll
    for (int k = 0; k < 8; k++) { o0[k] = (bf16)s[k]; o1[k] = (bf16)s[8 + k]; }
    bf16* dst = dG8 + (size_t)(b * N_C + c) * 4096 + threadIdx.x * 16;
    *(bf16x8*)dst = o0;
    *(bf16x8*)(dst + 8) = o1;
}

// ---------------------------------------------------------------------------
// K3': block (b, c, zz) -> out rows [c*64 + zz*16, +16). Register scan of
// dG8[b, t<c] (L2-hot, proven) -> Gb; wave w = i-block w: 2 prefix MFMAs;
// fp32 diag fold from diagq; store. 9 KB LDS. Grid (D_B, N_C, 4): %8 = b.
// ---------------------------------------------------------------------------
__global__ __launch_bounds__(256, 4) void k_out(
    const float* __restrict__ rp, const bf16* __restrict__ dG8,
    const float* __restrict__ diagq, float* __restrict__ out)
{
    __shared__ bf16 Gb[64 * NP];   // Gcum [i][i'] bf16
    const int b = blockIdx.x, c = blockIdx.y, zz = blockIdx.z;
    const int tid = threadIdx.x;
    const int w = tid >> 6, l = tid & 63, q = l >> 4, l16 = l & 15;

    // A-frags: r' rows t = c*64 + zz*16 + l16 (direct fp32, L2/L3-resident)
    const float* rr = rp + ((size_t)b * N_T + c * 64 + zz * 16 + l16) * NN;
    const bf16x8 ra0 = ldcvt8(rr + q * 8);
    const bf16x8 ra1 = ldcvt8(rr + 32 + q * 8);

    // diag fold (fp32): wave w owns i-block w
    float dsum[4];
#pragma unroll
    for (int r = 0; r < 4; r++) {
        float sgm = 0.f;
#pragma unroll
        for (int qt = 0; qt < 4; qt++)
            sgm += diagq[(((size_t)(b * N_C + c)) * 4 + qt) * 4096 +
                         (zz * 16 + q * 4 + r) * 64 + w * 16 + l16];
        dsum[r] = sgm;
    }

    // register scan of dG8[b, t<c] (L2-hot), batch-4
    float run[16];
#pragma unroll
    for (int k = 0; k < 16; k++) run[k] = 0.f;
    {
        const bf16* base = dG8 + (size_t)b * N_C * 4096 + tid * 16;
        int t = 0;
        for (; t + 4 <= c; t += 4) {
            bf16x8 v[4][2];
#pragma unroll
            for (int j = 0; j < 4; j++) {
                v[j][0] = *(const bf16x8*)(base + (size_t)(t + j) * 4096);
                v[j][1] = *(const bf16x8*)(base + (size_t)(t + j) * 4096 + 8);
            }
#pragma unroll
            for (int j = 0; j < 4; j++)
#pragma unroll
                for (int k = 0; k < 8; k++) {
                    run[k] += (float)v[j][0][k];
                    run[8 + k] += (float)v[j][1][k];
                }
        }
        for (; t < c; t++) {
            const bf16x8 v0 = *(const bf16x8*)(base + (size_t)t * 4096);
            const bf16x8 v1 = *(const bf16x8*)(base + (size_t)t * 4096 + 8);
#pragma unroll
            for (int k = 0; k < 8; k++) { run[k] += (float)v0[k]; run[8 + k] += (float)v1[k]; }
        }
    }
    {
        bf16x8 o0, o1;
#pragma unroll
        for (int k = 0; k < 8; k++) { o0[k] = (bf16)run[k]; o1[k] = (bf16)run[8 + k]; }
        *(bf16x8*)&Gb[(tid >> 2) * NP + (tid & 3) * 16]     = o0;
        *(bf16x8*)&Gb[(tid >> 2) * NP + (tid & 3) * 16 + 8] = o1;
    }
    __syncthreads();  // Gb ready
    f32x4 pacc = {0.f, 0.f, 0.f, 0.f};
    const bf16x8 g0 = *(const bf16x8*)&Gb[(w * 16 + l16) * NP + q * 8];
    const bf16x8 g1 = *(const bf16x8*)&Gb[(w * 16 + l16) * NP + 32 + q * 8];
    pacc = mfma16(ra0, g0, pacc);
    pacc = mfma16(ra1, g1, pacc);
#pragma unroll
    for (int r = 0; r < 4; r++)
        out[((size_t)b * N_T + c * 64 + zz * 16 + q * 4 + r) * NN + w * 16 + l16] =
            pacc[r] + dsum[r];
}

// ---------------------------------------------------------------------------
extern "C" void kernel_launch(void* const* d_in, const int* in_sizes, int n_in,
                              void* d_out, int out_size, void* d_ws, size_t ws_size,
                              hipStream_t stream) {
    const float* rp = (const float*)d_in[0];   // (8, 2048, 64) fp32
    const float* Qm = (const float*)d_in[1];   // (8, 64, 64)
    const float* Em = (const float*)d_in[2];   // (8, 64, 64)
    float* out = (float*)d_out;                // (8, 2048, 64) fp32

    // ws: dGq 8.4 MB (bf16) + diagq 16.8 MB (fp32) + dG8 2.1 MB (bf16)
    bf16* dGq = (bf16*)d_ws;
    float* diagq = (float*)(dGq + (size_t)D_B * N_C * 4 * 4096);
    bf16* dG8 = (bf16*)(diagq + (size_t)D_B * N_C * 4 * 4096);

    k_dg<<<dim3(D_B, N_C, 4), 256, 0, stream>>>(rp, Qm, Em, dGq, diagq);
    k_fold<<<dim3(D_B, N_C), 256, 0, stream>>>(dGq, dG8);
    k_out<<<dim3(D_B, N_C, 4), 256, 0, stream>>>(rp, dG8, diagq, out);
}

// Round 5
// 98.439 us; speedup vs baseline: 1.2291x; 1.2291x over previous
//
#include <hip/hip_runtime.h>

// Problem constants
#define D_B 8
#define N_T 2048
#define NN  64
#define N_H 8
#define N_C 32   // u-chunks of 64
#define NP  72   // padded LDS row stride (bf16): 144 B rows, 16B-aligned, 2-way alias (free)

typedef __bf16 bf16;
typedef bf16 bf16x8 __attribute__((ext_vector_type(8)));
typedef bf16 bf16x4 __attribute__((ext_vector_type(4)));
typedef float f32x4 __attribute__((ext_vector_type(4)));

static __device__ __forceinline__ f32x4 mfma16(bf16x8 a, bf16x8 b, f32x4 c) {
    // a_frag[j] = A[lane&15][(lane>>4)*8+j]; b_frag[j] = B[(lane>>4)*8+j][lane&15]
    // d[r] = D[(lane>>4)*4+r][lane&15]
    return __builtin_amdgcn_mfma_f32_16x16x32_bf16(a, b, c, 0, 0, 0);
}

static __device__ __forceinline__ bf16x8 ldcvt8(const float* p) {
    const f32x4 v0 = *(const f32x4*)p;
    const f32x4 v1 = *(const f32x4*)(p + 4);
    bf16x8 r;
#pragma unroll
    for (int k = 0; k < 4; k++) { r[k] = (bf16)v0[k]; r[4 + k] = (bf16)v1[k]; }
    return r;
}

// ---------------------------------------------------------------------------
// K1 (R5): 512 threads = TWO independent 4-wave groups, each running the
// R3-PROVEN 2-head pipeline (stage;A;Qr/Er;B;dG+QT2;C;diag+PV;D) on its own
// 36.9 KB LDS slab set. Group g of block (b,c,zz) handles heads
// {4zz+2g, 4zz+2g+1}. Both groups execute identical phase structure, so the
// shared __syncthreads cadence is unchanged. Tail: cross-group fp32 fold in
// LDS -> dGh (bf16, 2 partials per (b,c)) + diagh (fp32, 2 partials).
// k_fold is ELIMINATED. LDS 73.7 KB -> 2 blocks/CU = 16 waves/CU (same TLP
// as R3). Grid (D_B, N_C, 2): linear%8 = b (XCD-local).
// ---------------------------------------------------------------------------
__global__ __launch_bounds__(512, 4) void k_dg(
    const float* __restrict__ rp, const float* __restrict__ Qm,
    const float* __restrict__ Em,
    bf16* __restrict__ dGh, float* __restrict__ diagh)
{
    __shared__ __align__(16) char smem[2 * 4 * 64 * NP * 2];  // 73728 B
    const int b = blockIdx.x, c = blockIdx.y, zz = blockIdx.z;
    const int tid = threadIdx.x;
    const int g = tid >> 8, t8 = tid & 255;          // group, within-group tid
    bf16* Ql = (bf16*)smem + (size_t)g * 4 * 64 * NP;  // Q_h [i'][j]; later QT2 [u][i']
    bf16* El = Ql + 64 * NP;                           // E_h [i][j]; later S slabs
    bf16* QT = El + 64 * NP;                           // Qr [i'][u]; dG staging at tail
    bf16* ET = QT + 64 * NP;                           // Er [i][u]
    float* fst = (float*)Ql;                           // tail fp32 diag 64x66 (Ql+El)

    const int w = t8 >> 6, l = t8 & 63, q = l >> 4, l16 = l & 15;
    const int row = t8 >> 2, col = (t8 & 3) * 16;

    // A-frags: r' rows u = t = c*64 + w*16 + l16 (shared by Qr/Er/S paths)
    const float* rrow = rp + ((size_t)b * N_T + c * 64 + w * 16 + l16) * NN;
    const bf16x8 a0 = ldcvt8(rrow + q * 8);
    const bf16x8 a1 = ldcvt8(rrow + 32 + q * 8);

    f32x4 dacc[4], acc[4];
#pragma unroll
    for (int ns = 0; ns < 4; ns++) {
        f32x4 z = {0.f, 0.f, 0.f, 0.f};
        dacc[ns] = z; acc[ns] = z;
    }

    for (int hh = 0; hh < 2; hh++) {
        const int h = zz * 4 + g * 2 + hh;
        {
            const float* qs = Qm + (size_t)h * 4096 + row * 64 + col;
            const float* es = Em + (size_t)h * 4096 + row * 64 + col;
            *(bf16x8*)&Ql[row * NP + col]     = ldcvt8(qs);
            *(bf16x8*)&Ql[row * NP + col + 8] = ldcvt8(qs + 8);
            *(bf16x8*)&El[row * NP + col]     = ldcvt8(es);
            *(bf16x8*)&El[row * NP + col + 8] = ldcvt8(es + 8);
        }
        __syncthreads();  // A: Ql/El ready
        // Qr, Er for this wave's 16 u-rows; keep Qr bf16 in regs (pq)
        bf16x4 pq[4];
#pragma unroll
        for (int ns = 0; ns < 4; ns++) {
            bf16x8 b0 = *(const bf16x8*)&Ql[(ns * 16 + l16) * NP + q * 8];
            bf16x8 b1 = *(const bf16x8*)&Ql[(ns * 16 + l16) * NP + 32 + q * 8];
            f32x4 z = {0.f, 0.f, 0.f, 0.f};
            f32x4 s = mfma16(a0, b0, z);
            s = mfma16(a1, b1, s);
            bf16x4 p;
#pragma unroll
            for (int r = 0; r < 4; r++) p[r] = (bf16)s[r];
            pq[ns] = p;
            *(bf16x4*)&QT[(ns * 16 + l16) * NP + w * 16 + q * 4] = p;  // [i'][u]
            b0 = *(const bf16x8*)&El[(ns * 16 + l16) * NP + q * 8];
            b1 = *(const bf16x8*)&El[(ns * 16 + l16) * NP + 32 + q * 8];
            f32x4 s2 = mfma16(a0, b0, z);
            s2 = mfma16(a1, b1, s2);
#pragma unroll
            for (int r = 0; r < 4; r++) p[r] = (bf16)s2[r];
            *(bf16x4*)&ET[(ns * 16 + l16) * NP + w * 16 + q * 4] = p;  // [i][u]
        }
        __syncthreads();  // B: QT/ET ready; Ql/El now dead
        // dG += Qr^T.Er (reads QT/ET); in parallel write QT2 [u][i'] -> Ql
        {
            const bf16x8 qa0 = *(const bf16x8*)&QT[(w * 16 + l16) * NP + q * 8];
            const bf16x8 qa1 = *(const bf16x8*)&QT[(w * 16 + l16) * NP + 32 + q * 8];
#pragma unroll
            for (int ns = 0; ns < 4; ns++) {
                const bf16x8 e0 = *(const bf16x8*)&ET[(ns * 16 + l16) * NP + q * 8];
                const bf16x8 e1 = *(const bf16x8*)&ET[(ns * 16 + l16) * NP + 32 + q * 8];
                dacc[ns] = mfma16(qa0, e0, dacc[ns]);
                dacc[ns] = mfma16(qa1, e1, dacc[ns]);
            }
        }
#pragma unroll
        for (int ns = 0; ns < 4; ns++)
#pragma unroll
            for (int r = 0; r < 4; r++)
                Ql[(w * 16 + q * 4 + r) * NP + ns * 16 + l16] = pq[ns][r];
        __syncthreads();  // C: QT2 (Ql) ready; El dead -> per-wave S slabs
        // Diagonal: S[t][u] = mask(r_t . Qr_u^T), t in wave's 16 rows.
        // Reads cover: w=0 -> cols 0-31 (nu 0,1); w>=2 -> cols 0-63.
        // Zero-fill ONLY regions read but not written: (w==0,nu==1),(w==2,nu==3).
        {
            bf16* Sw = El + (w * 16) * NP;   // this wave's 16-row slab
#pragma unroll
            for (int nu = 0; nu < 4; nu++) {
                if (nu <= w) {
                    const bf16x8 b0 = *(const bf16x8*)&Ql[(nu * 16 + l16) * NP + q * 8];
                    const bf16x8 b1 = *(const bf16x8*)&Ql[(nu * 16 + l16) * NP + 32 + q * 8];
                    f32x4 z = {0.f, 0.f, 0.f, 0.f};
                    f32x4 sv = mfma16(a0, b0, z);
                    sv = mfma16(a1, b1, sv);
                    const int u_loc = nu * 16 + l16;
#pragma unroll
                    for (int r = 0; r < 4; r++) {
                        const int t_loc = w * 16 + q * 4 + r;
                        Sw[(q * 4 + r) * NP + u_loc] = (u_loc <= t_loc) ? (bf16)sv[r] : (bf16)0.f;
                    }
                } else if ((w == 0 && nu == 1) || (w == 2 && nu == 3)) {
#pragma unroll
                    for (int r = 0; r < 4; r++)
                        Sw[(q * 4 + r) * NP + nu * 16 + l16] = (bf16)0.f;
                }
            }
            // same-wave in-order DS read-back; PV: acc += S.Er
            const bf16x8 sa0 = *(const bf16x8*)&Sw[l16 * NP + q * 8];
#pragma unroll
            for (int ns = 0; ns < 4; ns++) {
                const bf16x8 e0 = *(const bf16x8*)&ET[(ns * 16 + l16) * NP + q * 8];
                acc[ns] = mfma16(sa0, e0, acc[ns]);
            }
            if (w >= 2) {
                const bf16x8 sa1 = *(const bf16x8*)&Sw[l16 * NP + 32 + q * 8];
#pragma unroll
                for (int ns = 0; ns < 4; ns++) {
                    const bf16x8 e1 = *(const bf16x8*)&ET[(ns * 16 + l16) * NP + 32 + q * 8];
                    acc[ns] = mfma16(sa1, e1, acc[ns]);
                }
            }
        }
        __syncthreads();  // D: end of head (Ql/El/QT/ET reused next iter)
    }
    // ---- tail: per-group stage dG (bf16 [i][i'] -> QT) and diag (fp32 -> fst)
#pragma unroll
    for (int ns = 0; ns < 4; ns++) {
        bf16x4 p;
#pragma unroll
        for (int r = 0; r < 4; r++) p[r] = (bf16)dacc[ns][r];
        *(bf16x4*)&QT[(ns * 16 + l16) * NP + w * 16 + q * 4] = p;
    }
#pragma unroll
    for (int ns = 0; ns < 4; ns++)
#pragma unroll
        for (int r = 0; r < 4; r++)
            fst[(w * 16 + q * 4 + r) * 66 + ns * 16 + l16] = acc[ns][r];
    __syncthreads();
    // ---- cross-group fold (all 512 threads; 8 elems each) -> dGh, diagh
    {
        const int rr2 = tid >> 3, cc2 = (tid & 7) * 8;
        const bf16* QT0 = (const bf16*)smem + 2 * 64 * NP;
        const bf16* QT1 = (const bf16*)smem + 4 * 64 * NP + 2 * 64 * NP;
        const float* f0 = (const float*)smem;
        const float* f1 = (const float*)((const bf16*)smem + 4 * 64 * NP);
        const bf16x8 d0 = *(const bf16x8*)&QT0[rr2 * NP + cc2];
        const bf16x8 d1 = *(const bf16x8*)&QT1[rr2 * NP + cc2];
        bf16x8 o;
#pragma unroll
        for (int k = 0; k < 8; k++) o[k] = (bf16)((float)d0[k] + (float)d1[k]);
        const size_t tb = (((size_t)(b * N_C + c)) * 2 + zz) * 4096 + rr2 * 64 + cc2;
        *(bf16x8*)(dGh + tb) = o;
        float ds[8];
#pragma unroll
        for (int k = 0; k < 8; k++)
            ds[k] = f0[rr2 * 66 + cc2 + k] + f1[rr2 * 66 + cc2 + k];
        *(f32x4*)(diagh + tb)     = *(const f32x4*)&ds[0];
        *(f32x4*)(diagh + tb + 4) = *(const f32x4*)&ds[4];
    }
}

// ---------------------------------------------------------------------------
// K2 (R5): block (b, c, zz) -> out rows [c*64 + zz*16, +16). Register scan of
// the TWO dGh partial streams for t<c (L2-hot; replaces k_fold + dG8 scan);
// wave w = i-block w: 2 prefix MFMAs; fp32 diag fold from the 2 diagh
// partials; store. 9 KB LDS. Grid (D_B, N_C, 4): linear%8 = b.
// ---------------------------------------------------------------------------
__global__ __launch_bounds__(256, 4) void k_out(
    const float* __restrict__ rp, const bf16* __restrict__ dGh,
    const float* __restrict__ diagh, float* __restrict__ out)
{
    __shared__ bf16 Gb[64 * NP];   // Gcum [i][i'] bf16
    const int b = blockIdx.x, c = blockIdx.y, zz = blockIdx.z;
    const int tid = threadIdx.x;
    const int w = tid >> 6, l = tid & 63, q = l >> 4, l16 = l & 15;

    // A-frags: r' rows t = c*64 + zz*16 + l16 (direct fp32, L2/L3-resident)
    const float* rr = rp + ((size_t)b * N_T + c * 64 + zz * 16 + l16) * NN;
    const bf16x8 ra0 = ldcvt8(rr + q * 8);
    const bf16x8 ra1 = ldcvt8(rr + 32 + q * 8);

    // diag fold (fp32): wave w owns i-block w; 2 partials
    float dsum[4];
#pragma unroll
    for (int r = 0; r < 4; r++) {
        const size_t di = (((size_t)(b * N_C + c)) * 2) * 4096 +
                          (zz * 16 + q * 4 + r) * 64 + w * 16 + l16;
        dsum[r] = diagh[di] + diagh[di + 4096];
    }

    // register scan of the 2 dGh streams for t<c (L2-hot), batch-2 over t
    float run[16];
#pragma unroll
    for (int k = 0; k < 16; k++) run[k] = 0.f;
    {
        const bf16* base = dGh + (size_t)b * N_C * 2 * 4096 + tid * 16;
        int t = 0;
        for (; t + 2 <= c; t += 2) {
            bf16x8 v[4][2];
#pragma unroll
            for (int j = 0; j < 4; j++) {   // j = (t-offset<<1)|partial
                const size_t off = (size_t)((t + (j >> 1)) * 2 + (j & 1)) * 4096;
                v[j][0] = *(const bf16x8*)(base + off);
                v[j][1] = *(const bf16x8*)(base + off + 8);
            }
#pragma unroll
            for (int j = 0; j < 4; j++)
#pragma unroll
                for (int k = 0; k < 8; k++) {
                    run[k] += (float)v[j][0][k];
                    run[8 + k] += (float)v[j][1][k];
                }
        }
        for (; t < c; t++) {
#pragma unroll
            for (int p = 0; p < 2; p++) {
                const size_t off = (size_t)(t * 2 + p) * 4096;
                const bf16x8 v0 = *(const bf16x8*)(base + off);
                const bf16x8 v1 = *(const bf16x8*)(base + off + 8);
#pragma unroll
                for (int k = 0; k < 8; k++) { run[k] += (float)v0[k]; run[8 + k] += (float)v1[k]; }
            }
        }
    }
    {
        bf16x8 o0, o1;
#pragma unroll
        for (int k = 0; k < 8; k++) { o0[k] = (bf16)run[k]; o1[k] = (bf16)run[8 + k]; }
        *(bf16x8*)&Gb[(tid >> 2) * NP + (tid & 3) * 16]     = o0;
        *(bf16x8*)&Gb[(tid >> 2) * NP + (tid & 3) * 16 + 8] = o1;
    }
    __syncthreads();  // Gb ready
    f32x4 pacc = {0.f, 0.f, 0.f, 0.f};
    const bf16x8 g0 = *(const bf16x8*)&Gb[(w * 16 + l16) * NP + q * 8];
    const bf16x8 g1 = *(const bf16x8*)&Gb[(w * 16 + l16) * NP + 32 + q * 8];
    pacc = mfma16(ra0, g0, pacc);
    pacc = mfma16(ra1, g1, pacc);
#pragma unroll
    for (int r = 0; r < 4; r++)
        out[((size_t)b * N_T + c * 64 + zz * 16 + q * 4 + r) * NN + w * 16 + l16] =
            pacc[r] + dsum[r];
}

// ---------------------------------------------------------------------------
extern "C" void kernel_launch(void* const* d_in, const int* in_sizes, int n_in,
                              void* d_out, int out_size, void* d_ws, size_t ws_size,
                              hipStream_t stream) {
    const float* rp = (const float*)d_in[0];   // (8, 2048, 64) fp32
    const float* Qm = (const float*)d_in[1];   // (8, 64, 64)
    const float* Em = (const float*)d_in[2];   // (8, 64, 64)
    float* out = (float*)d_out;                // (8, 2048, 64) fp32

    // ws: dGh 4.2 MB (bf16, 2 partials) + diagh 8.4 MB (fp32, 2 partials)
    bf16* dGh = (bf16*)d_ws;
    float* diagh = (float*)(dGh + (size_t)D_B * N_C * 2 * 4096);

    k_dg<<<dim3(D_B, N_C, 2), 512, 0, stream>>>(rp, Qm, Em, dGh, diagh);
    k_out<<<dim3(D_B, N_C, 4), 256, 0, stream>>>(rp, dGh, diagh, out);
}